// Round 7
// baseline (310.608 us; speedup 1.0000x reference)
//
#include <hip/hip_runtime.h>

// GlobalFilter (GFNet): out = irfft2(rfft2(x)·W, ortho) == per-channel 16x16
// circular convolution with k[:,:,c] = inverse transform of W. ortho norms cancel.
//
// Lessons:
//  R1: k reads are a per-lane GATHER -> k MUST stay in LDS. x rows are
//      n-independent broadcasts/coalesced -> LDS optional for x.
//  R2: dynamic reg-array index -> scratch. Only compile-time indices.
//  R3: conditionals in hot unrolled loops -> spill. Branch-free bodies only.
//  R4 (conv 184): 64 KB LDS -> 1 wave/SIMD, VGPR 132 (kv register-resident).
//  R5 (conv 149): x column in LDS + 16 barriers. Occ 27%, VALUBusy 66%.
//      VGPR dropped to 84!
//  R6/R7 (3010/2757 total): __launch_bounds__(256,4) caps regfile at 128 <
//      live set -> degenerate 64-VGPR spill (WRITE 6-9 GB). Max 3 waves/SIMD.
//  R8 (conv 296): x direct global, no prefetch: 1 load in flight, serialized
//      on L2 latency. VALUBusy 32%.
//  R9 (conv 176): 4-deep x register ring fixed the x latency (VALUBusy 56)
//      but VGPR STILL 84 = acc(64)+ring(16)+addr: kv[16] is NOT in registers
//      in the 256-thread structure - compiler re-reads k from LDS inside the
//      d-loop. The CU's single LDS port (~12cy/b128, shared by 4 SIMDs) is
//      the real thing pinning VALUBusy at 50-66% since R5. R4's VGPR=132
//      proves the allocator CAN hold kv; its heuristic just won't here.
//  R10 (compile fail): asm "+v" on float4 -> "tied indirect register inputs"
//      not supported. LESSON: opaque-asm pinning must be PER-SCALAR operand;
//      vector types fail the operand binder.
//  R11 (this version): same pin, per-component: asm("" : "+v"(kv[p].x), ...).
//      A value an asm may have modified cannot be re-read from LDS -> all 64
//      kv VGPRs stay live. Live set acc64+kv64+ring16+addr ~= 152 <= 170
//      (3 waves/SIMD cap). LDS traffic drops to 16 b128/qq/wave (~190cy vs
//      2048cy FMA): LDS falls off the critical path; VALU becomes the limit.

constexpr int PP = 16;   // patch size
constexpr int NS = 256;  // PP*PP spatial
constexpr int CH = 768;  // channels
constexpr int NB = 128;  // batch

// async global->LDS, 16B per lane. lds ptr must be wave-uniform base; HW adds
// lane*16. Source address is per-lane. (Used only for the ks gather tile.)
__device__ __forceinline__ void cp_g2s_16(const void* g, void* s) {
    __builtin_amdgcn_global_load_lds(
        (const __attribute__((address_space(1))) void*)g,
        (__attribute__((address_space(3))) void*)s, 16, 0, 0);
}

// ---------------- Kernel A: build real conv kernel k[p*16+q][c] -------------
__global__ void gf_build_k(const float* __restrict__ w, float* __restrict__ kbuf) {
    __shared__ float ct[16], st[16];
    if (threadIdx.x < 16) {
        const float ang = 6.28318530717958647692f * (float)threadIdx.x * (1.0f / 16.0f);
        ct[threadIdx.x] = cosf(ang);
        st[threadIdx.x] = sinf(ang);
    }
    __syncthreads();

    const int pq = blockIdx.x;                              // 0..255
    const int c  = blockIdx.y * blockDim.x + threadIdx.x;   // 0..767
    const int p = pq >> 4, q = pq & 15;

    float acc = 0.0f;
#pragma unroll 1
    for (int u = 0; u < 16; ++u) {
        const float* wu = w + (size_t)(u * 9) * 2 * CH + 2 * c;
#pragma unroll
        for (int v = 0; v < 9; ++v) {
            const float cv = (v == 0 || v == 8) ? 1.0f : 2.0f;
            const int t = (u * p + v * q) & 15;  // lane-uniform -> LDS broadcast
            const float wr = wu[(size_t)v * 2 * CH];
            const float wi = wu[(size_t)v * 2 * CH + 1];
            acc += cv * (wr * ct[t] - wi * st[t]);
        }
    }
    kbuf[pq * CH + c] = acc * (1.0f / 256.0f);
}

// ---------------- Kernel B: depthwise 16x16 circular conv -------------------
// block = 256 threads = 2 batches x (8 ch-groups x 16 n-cols). 32 KB LDS:
//   ks[256][32]  (per-lane gather -> LDS, staged once, read-only after)
// x streamed from global through a 4-deep register ring; kv pinned in regs
// via per-scalar opaque asm. One barrier total (after ks staging).
__global__ __launch_bounds__(256, 3) void gf_conv(const float* __restrict__ x,
                                                  const float* __restrict__ kbuf,
                                                  float* __restrict__ out) {
    __shared__ __align__(16) float ks[NS][32];

    const int tid  = threadIdx.x;
    const int half = tid >> 7;                 // batch half 0/1
    const int b    = (blockIdx.y << 1) | half;
    const int c0   = blockIdx.x * 32;
    const int wave = tid >> 6;                 // 0..3 (wave-uniform)

    // ---- stage k tile: 8 x global_load_lds per thread, lane-linear dest.
    {
        const int srow = tid >> 3;             // 0..31
        const int kch4 = (tid & 7) << 2;
        const float* kb = kbuf + c0;
        float* lbase = &ks[0][0] + wave * 256; // 1 KB per wave, uniform
#pragma unroll
        for (int i = 0; i < 8; ++i)
            cp_g2s_16(kb + (size_t)(i * 32 + srow) * CH + kch4, lbase + i * 1024);
    }
    __syncthreads();  // ks staged. Last barrier in the kernel.

    const int chq = (tid & 7) << 2;   // channel float4 within tile
    const int n   = (tid >> 3) & 15;  // output column 0..15
    const float* xb = x + (size_t)b * NS * CH + c0 + chq;

    float4 acc[16];
#pragma unroll
    for (int m = 0; m < 16; ++m) acc[m] = make_float4(0.f, 0.f, 0.f, 0.f);

    // ---- prime the ring: rows 0..3 of column j=0
    float4 xq[4];  // static-indexed ring (R2: all indices compile-time)
#pragma unroll
    for (int i = 0; i < 4; ++i)
        xq[i] = *(const float4*)(xb + (size_t)(i << 4) * CH);

    int j = 0, jn = 15;  // current / next x column (j(qq) = (16-qq)&15)

#pragma unroll 1
    for (int qq = 0; qq < 16; ++qq) {
        const int q = (qq + n) & 15;   // lane-varying k column
        const float* colp = xb + (size_t)j * CH;   // current column base
        const float* coln = xb + (size_t)jn * CH;  // next column base

        // kv[16]: 16 distinct-address b128 LDS reads, then PIN in registers.
        // Per-scalar opaque "+v" touch (R10: vector operands unsupported):
        // a value an asm may have modified cannot be rematerialized or
        // re-read from LDS -> all 64 kv VGPRs stay live through the d-loop.
        float4 kv[16];
#pragma unroll
        for (int p = 0; p < 16; ++p)
            kv[p] = *(const float4*)&ks[(p << 4) | q][chq];
#pragma unroll
        for (int p = 0; p < 16; ++p)
            asm volatile("" : "+v"(kv[p].x), "+v"(kv[p].y), "+v"(kv[p].z), "+v"(kv[p].w));

        // d-loop fully unrolled: consume xq[d&3] = row(d, j); refill slot with
        // row (d+4)&15 -- of col j for d<12, of col jn for d>=12 (prefetch
        // across the qq boundary). (d<12) resolves at compile time: no branch.
#pragma unroll
        for (int d = 0; d < 16; ++d) {
            const float4 xx = xq[d & 3];
            const float* src = (d < 12) ? colp : coln;
            xq[d & 3] = *(const float4*)(src + (size_t)((((d + 4) & 15)) << 4) * CH);
#pragma unroll
            for (int p = 0; p < 16; ++p) {
                const int m = (p + d) & 15;  // compile-time
                acc[m].x = fmaf(kv[p].x, xx.x, acc[m].x);
                acc[m].y = fmaf(kv[p].y, xx.y, acc[m].y);
                acc[m].z = fmaf(kv[p].z, xx.z, acc[m].z);
                acc[m].w = fmaf(kv[p].w, xx.w, acc[m].w);
            }
        }

        j = jn;
        jn = (jn - 1) & 15;
    }

    float* ob = out + (size_t)b * NS * CH + c0 + chq;
#pragma unroll
    for (int m = 0; m < 16; ++m)
        *(float4*)(ob + (size_t)((m << 4) + n) * CH) = acc[m];
}

// ---------------------------------------------------------------------------
extern "C" void kernel_launch(void* const* d_in, const int* in_sizes, int n_in,
                              void* d_out, int out_size, void* d_ws, size_t ws_size,
                              hipStream_t stream) {
    const float* x = (const float*)d_in[0];        // [128, 256, 768] fp32
    const float* w = (const float*)d_in[1];        // [16, 9, 768, 2] fp32
    float* out  = (float*)d_out;                   // [128, 256, 768] fp32
    float* kbuf = (float*)d_ws;                    // 256*768 fp32 = 768 KB

    gf_build_k<<<dim3(256, 3), 256, 0, stream>>>(w, kbuf);
    gf_conv<<<dim3(CH / 32, NB / 2), 256, 0, stream>>>(x, kbuf, out);
}

// Round 8
// 278.247 us; speedup vs baseline: 1.1163x; 1.1163x over previous
//
#include <hip/hip_runtime.h>

// GlobalFilter (GFNet): out = irfft2(rfft2(x)·W, ortho) == per-channel 16x16
// circular convolution with k[:,:,c] = inverse transform of W. ortho norms cancel.
//
// Lessons:
//  R1: k reads are a per-lane GATHER -> k MUST stay in LDS. x rows are
//      n-independent broadcasts/coalesced -> LDS optional for x.
//  R2: dynamic reg-array index -> scratch. Only compile-time indices.
//  R3: conditionals in hot unrolled loops -> spill. Branch-free bodies only.
//  R4 (conv 184): 64 KB LDS -> 1 wave/SIMD, VGPR 132.
//  R5 (conv 149): x column in LDS, prefetched 1 qq ahead, but 16 block-wide
//      barriers re-sync all 4 waves every iteration. Occ 27%, VALUBusy 66%.
//  R6/R7 (3010/2757 total): __launch_bounds__(256,4) caps regfile at 128 <
//      live set -> degenerate 64-VGPR spill (WRITE 6-9 GB). Max 3 waves/SIMD.
//  R8 (conv 296): x direct global, no prefetch: serialized on memory latency.
//  R9 (conv 176): 4-deep x register ring: better (VALUBusy 56) but ~512-cycle
//      cover < L3/HBM latency (FETCH 50MB -> half of x misses to HBM ~900cy).
//  R10/R11: kv pin via opaque asm - per-scalar "+v" compiles (float4 fails
//      the operand binder) but changed NOTHING (VGPR 84, VALUBusy 56).
//      LESSON: VGPR_Count excludes AGPRs on gfx950's unified file; kv/acc
//      were already resident. The bottleneck was x-latency all along.
//  R12 (this version): R5's deep cover + R8's decoupling, simultaneously.
//      x double-buffer made WAVE-PRIVATE (xw[4][2][16][32], 16 KB): staging
//      issued a full qq iteration (~2048 issue-cy) ahead via global_load_lds,
//      and each wave waits only on ITS OWN loads with s_waitcnt vmcnt(0)
//      (asm + "memory" clobber orders ds ops across it). ZERO block barriers
//      in the loop. LDS 48 KB -> still 3 blocks/CU. Floor ~85 us at overlap.

constexpr int PP = 16;   // patch size
constexpr int NS = 256;  // PP*PP spatial
constexpr int CH = 768;  // channels
constexpr int NB = 128;  // batch

// async global->LDS, 16B per lane. lds ptr must be wave-uniform base; HW adds
// lane*16. Source address is per-lane.
__device__ __forceinline__ void cp_g2s_16(const void* g, void* s) {
    __builtin_amdgcn_global_load_lds(
        (const __attribute__((address_space(1))) void*)g,
        (__attribute__((address_space(3))) void*)s, 16, 0, 0);
}

// ---------------- Kernel A: build real conv kernel k[p*16+q][c] -------------
__global__ void gf_build_k(const float* __restrict__ w, float* __restrict__ kbuf) {
    __shared__ float ct[16], st[16];
    if (threadIdx.x < 16) {
        const float ang = 6.28318530717958647692f * (float)threadIdx.x * (1.0f / 16.0f);
        ct[threadIdx.x] = cosf(ang);
        st[threadIdx.x] = sinf(ang);
    }
    __syncthreads();

    const int pq = blockIdx.x;                              // 0..255
    const int c  = blockIdx.y * blockDim.x + threadIdx.x;   // 0..767
    const int p = pq >> 4, q = pq & 15;

    float acc = 0.0f;
#pragma unroll 1
    for (int u = 0; u < 16; ++u) {
        const float* wu = w + (size_t)(u * 9) * 2 * CH + 2 * c;
#pragma unroll
        for (int v = 0; v < 9; ++v) {
            const float cv = (v == 0 || v == 8) ? 1.0f : 2.0f;
            const int t = (u * p + v * q) & 15;  // lane-uniform -> LDS broadcast
            const float wr = wu[(size_t)v * 2 * CH];
            const float wi = wu[(size_t)v * 2 * CH + 1];
            acc += cv * (wr * ct[t] - wi * st[t]);
        }
    }
    kbuf[pq * CH + c] = acc * (1.0f / 256.0f);
}

// ---------------- Kernel B: depthwise 16x16 circular conv -------------------
// block = 256 threads = 4 waves; waves 0,1 -> batch b0 (n 0-7 / 8-15),
// waves 2,3 -> batch b1. 48 KB LDS:
//   ks[256][32]       32 KB  (per-lane gather -> LDS, staged once)
//   xw[4][2][16][32]  16 KB  (wave-PRIVATE double-buffered x column)
// Loop: stage next column (2 global_load_lds) -> compute current -> wait own
// vmcnt(0). No block-wide barriers after init.
__global__ __launch_bounds__(256, 3) void gf_conv(const float* __restrict__ x,
                                                  const float* __restrict__ kbuf,
                                                  float* __restrict__ out) {
    __shared__ __align__(16) float ks[NS][32];
    __shared__ __align__(16) float xw[4][2][16][32];  // [wave][buf][row][ch]

    const int tid  = threadIdx.x;
    const int wave = tid >> 6;                 // 0..3 (wave-uniform)
    const int lane = tid & 63;
    const int b    = (blockIdx.y << 1) | (wave >> 1);
    const int c0   = blockIdx.x * 32;

    // ---- stage k tile: 8 x global_load_lds per thread, lane-linear dest.
    {
        const int srow = tid >> 3;             // 0..31
        const int kch4 = (tid & 7) << 2;
        const float* kb = kbuf + c0;
        float* lbase = &ks[0][0] + wave * 256; // 1 KB per wave, uniform
#pragma unroll
        for (int i = 0; i < 8; ++i)
            cp_g2s_16(kb + (size_t)(i * 32 + srow) * CH + kch4, lbase + i * 1024);
    }

    // per-lane x staging source: row block (lane>>3), channel 16B (lane&7).
    // lane l of instr t covers x[b, (t*8 + (l>>3))*16 + j, c0+(l&7)*4 ..+3]
    // -> LDS offset t*1024 + l*16 (lane-linear). 2 instrs = one 2 KB column.
    const float* xsrc = x + (size_t)b * NS * CH + c0
                        + (size_t)(lane >> 3) * 16 * CH + ((lane & 7) << 2);

    // ---- stage x column j(0)=0 into buf 0 (covered by the single barrier)
    cp_g2s_16(xsrc,                 &xw[wave][0][0][0]);
    cp_g2s_16(xsrc + 128 * CH,      &xw[wave][0][8][0]);

    __syncthreads();  // drains vmcnt(0): ks + col0 landed. LAST block barrier.

    const int chq = (tid & 7) << 2;   // channel float4 within tile
    const int n   = (tid >> 3) & 15;  // output column 0..15

    float4 acc[16];
#pragma unroll
    for (int m = 0; m < 16; ++m) acc[m] = make_float4(0.f, 0.f, 0.f, 0.f);

    int cb = 0;       // current buffer
    int jn = 15;      // next column: j(qq) = (16-qq)&15 -> j(qq+1)
#pragma unroll 1
    for (int qq = 0; qq < 16; ++qq) {
        // stage next column jn into buf cb^1 (qq=15 restages col0: branch-free)
        {
            const float* s0 = xsrc + (size_t)jn * CH;
            float* dst = &xw[wave][cb ^ 1][0][0];
            cp_g2s_16(s0,            dst);
            cp_g2s_16(s0 + 128 * CH, dst + 8 * 32);
        }

        const int q = (qq + n) & 15;   // lane-varying k column

        // kv[16]: distinct-address b128 LDS reads (conflict-free, measured 0)
        float4 kv[16];
#pragma unroll
        for (int p = 0; p < 16; ++p)
            kv[p] = *(const float4*)&ks[(p << 4) | q][chq];

        // d = (m - p) & 15: one broadcast LDS x row per d, indices static
        const float4* xrow = (const float4*)&xw[wave][cb][0][chq];
#pragma unroll
        for (int d = 0; d < 16; ++d) {
            const float4 xx = xrow[d * 8];  // row stride 32 floats = 8 float4
#pragma unroll
            for (int p = 0; p < 16; ++p) {
                const int m = (p + d) & 15;  // compile-time
                acc[m].x = fmaf(kv[p].x, xx.x, acc[m].x);
                acc[m].y = fmaf(kv[p].y, xx.y, acc[m].y);
                acc[m].z = fmaf(kv[p].z, xx.z, acc[m].z);
                acc[m].w = fmaf(kv[p].w, xx.w, acc[m].w);
            }
        }

        // wait for THIS WAVE's staging only; "memory" clobber keeps the next
        // iteration's ds_reads / staging from crossing. No block barrier.
        asm volatile("s_waitcnt vmcnt(0)" ::: "memory");
        cb ^= 1;
        jn = (jn - 1) & 15;
    }

    float* ob = out + (size_t)b * NS * CH + c0 + chq;
#pragma unroll
    for (int m = 0; m < 16; ++m)
        *(float4*)(ob + (size_t)((m << 4) + n) * CH) = acc[m];
}

// ---------------------------------------------------------------------------
extern "C" void kernel_launch(void* const* d_in, const int* in_sizes, int n_in,
                              void* d_out, int out_size, void* d_ws, size_t ws_size,
                              hipStream_t stream) {
    const float* x = (const float*)d_in[0];        // [128, 256, 768] fp32
    const float* w = (const float*)d_in[1];        // [16, 9, 768, 2] fp32
    float* out  = (float*)d_out;                   // [128, 256, 768] fp32
    float* kbuf = (float*)d_ws;                    // 256*768 fp32 = 768 KB

    gf_build_k<<<dim3(256, 3), 256, 0, stream>>>(w, kbuf);
    gf_conv<<<dim3(CH / 32, NB / 2), 256, 0, stream>>>(x, kbuf, out);
}